// Round 1
// 834.926 us; speedup vs baseline: 1.0079x; 1.0079x over previous
//
#include <hip/hip_runtime.h>
#include <math.h>

#define NN 100000
#define NE 1600000
#define NEG_SLOPE 0.2f

typedef __attribute__((ext_vector_type(8))) short bf16x8;
typedef __attribute__((ext_vector_type(4))) float f32x4;
typedef __attribute__((ext_vector_type(2))) float f32x2;

__device__ __forceinline__ float b2f(unsigned short u) {
  union { unsigned u; float f; } c; c.u = ((unsigned)u) << 16; return c.f;
}
__device__ __forceinline__ unsigned short f2b(float x) {
  union { float f; unsigned u; } c; c.f = x;
  unsigned r = c.u + 0x7FFFu + ((c.u >> 16) & 1u);
  return (unsigned short)(r >> 16);
}
__device__ __forceinline__ void fma4(float4& acc, float s, const float4& b) {
  acc.x = fmaf(s, b.x, acc.x);
  acc.y = fmaf(s, b.y, acc.y);
  acc.z = fmaf(s, b.z, acc.z);
  acc.w = fmaf(s, b.w, acc.w);
}
__device__ __forceinline__ float wred(float v) {
#pragma unroll
  for (int off = 32; off > 0; off >>= 1) v += __shfl_xor(v, off, 64);
  return v;
}

// ---------------- utility ----------------
__global__ __launch_bounds__(256) void k_zero(int* __restrict__ p, int nwords) {
  int i = blockIdx.x * 256 + threadIdx.x;
  if (i < nwords) p[i] = 0;
}

// zero the dummy rows (index NN) of the bf16 ping-pong buffers
__global__ void k_zrow(unsigned short* __restrict__ a, unsigned short* __restrict__ b) {
  int i = threadIdx.x;
  a[(size_t)NN * 64 + i] = 0;
  b[(size_t)NN * 64 + i] = 0;
}

__global__ __launch_bounds__(256) void k_cast(const float* __restrict__ A, unsigned short* __restrict__ Ab) {
  int i = blockIdx.x * 256 + threadIdx.x;
  int i4 = i * 4;
  if (i4 < NN * 128) {
    float4 v = *(const float4*)&A[i4];
    ushort4 o; o.x = f2b(v.x); o.y = f2b(v.y); o.z = f2b(v.z); o.w = f2b(v.w);
    *(ushort4*)&Ab[i4] = o;
  }
}

// ---------------- CSR build (unordered within row) ----------------
__global__ __launch_bounds__(256) void k_deg(const int* __restrict__ dst, int* __restrict__ deg) {
  int i = blockIdx.x * 256 + threadIdx.x;
  if (i < NE) atomicAdd(&deg[dst[i]], 1);
}

__global__ __launch_bounds__(256) void k_alloc(const int* __restrict__ deg, int* __restrict__ row_start,
                                               int* __restrict__ counter, float* __restrict__ nrm) {
  int i = blockIdx.x * 256 + threadIdx.x;
  if (i < NN) {
    row_start[i] = atomicAdd(counter, deg[i]);
    nrm[i] = rsqrtf(fmaxf((float)deg[i], 1.0f));
  }
}

__global__ __launch_bounds__(256) void k_scatter(const int* __restrict__ src, const int* __restrict__ dst,
                                                 const int* __restrict__ row_start, int* __restrict__ cursor,
                                                 int* __restrict__ csr_src) {
  int i = blockIdx.x * 256 + threadIdx.x;
  if (i < NE) {
    int n = dst[i];
    int p = atomicAdd(&cursor[n], 1);
    csr_src[row_start[n] + p] = src[i];
  }
}

// ---------------- fold attention vectors into W_fc: w[p][k], p = side*4+h ----------------
__global__ __launch_bounds__(256) void k_prepw(const float* __restrict__ W_fc, const float* __restrict__ al,
                                               const float* __restrict__ ar, float* __restrict__ w) {
  int o = blockIdx.x * 256 + threadIdx.x;  // [0,1024)
  if (o >= 1024) return;
  int side = o >> 9;
  int h = (o >> 7) & 3;
  int k = o & 127;
  const float* a = side ? ar : al;
  float s = 0.f;
  for (int d = 0; d < 64; ++d) s += W_fc[k * 256 + h * 64 + d] * a[h * 64 + d];
  w[(side * 4 + h) * 128 + k] = s;
}

// ---------------- exact el/er GEMV: thread = (node, p) ----------------
__global__ __launch_bounds__(256) void k_elr2(const float* __restrict__ X, const float* __restrict__ w,
                                              float* __restrict__ el, float* __restrict__ er) {
  int n = blockIdx.x * 32 + (threadIdx.x >> 3);
  int p = threadIdx.x & 7;
  if (n >= NN) return;
  const float4* xr = (const float4*)(X + (size_t)n * 128);
  const float4* wr = (const float4*)(w + p * 128);
  float s = 0.f;
#pragma unroll
  for (int i = 0; i < 32; ++i) {
    float4 x = xr[i], ww = wr[i];
    s += x.x * ww.x + x.y * ww.y + x.z * ww.z + x.w * ww.w;
  }
  if (p < 4) el[n * 4 + p] = s;
  else er[n * 4 + (p - 4)] = s;
}

// ---------------- pre-pack B (both weight mats) into MFMA fragment order ----------------
__global__ __launch_bounds__(256) void k_prepB(const float* __restrict__ W_fc, const float* __restrict__ W_rg,
                                               unsigned short* __restrict__ Bp) {
  int y = blockIdx.y;
  const float* Bsrc = (y >> 1) ? W_rg : W_fc;
  int colbase = (y & 1) * 128;
  for (int e = blockIdx.x * 256 + threadIdx.x; e < 16384; e += 2048) {
    int n = e & 127, k = e >> 7;
    int p = colbase + n;
    int d = p >> 2, hh = p & 3;
    float v = Bsrc[k * 256 + hh * 64 + d];
    int nt = n >> 4, nn = n & 15, kt = k >> 5, quad = (k >> 3) & 3, j = k & 7;
    Bp[(size_t)y * 16384 + ((nt * 4 + kt) * 64 + quad * 16 + nn) * 8 + j] = f2b(v);
  }
}

// ---------------- merged bf16 MFMA GEMM ----------------
// y=0,1 -> feat8 (fp8, (n,d,h) interleaved); y=2,3 -> resval2 (bf16 interleaved)
__global__ __launch_bounds__(256) void k_gemm_mfma(const unsigned short* __restrict__ Abf,
                                                   const unsigned short* __restrict__ Bp,
                                                   unsigned* __restrict__ feat8u,
                                                   unsigned short* __restrict__ resval2) {
  __shared__ unsigned short Bl[16384];
  int tid = threadIdx.x;
  int half = blockIdx.y >> 1;
  int colbase = (blockIdx.y & 1) * 128;
  {
    const uint4* src = (const uint4*)(Bp + (size_t)blockIdx.y * 16384);
    uint4* dst4 = (uint4*)Bl;
#pragma unroll
    for (int i = 0; i < 8; ++i) dst4[tid + i * 256] = src[tid + i * 256];
  }
  __syncthreads();
  int w = tid >> 6, lane = tid & 63;
  int quad = lane >> 4;
  int row0 = blockIdx.x * 128;
  int mrow = row0 + (lane & 15);
  f32x4 acc[8][2];
#pragma unroll
  for (int rt = 0; rt < 8; ++rt)
#pragma unroll
    for (int c = 0; c < 2; ++c) acc[rt][c] = (f32x4){0.f, 0.f, 0.f, 0.f};
#pragma unroll
  for (int kt = 0; kt < 4; ++kt) {
    bf16x8 b0 = *(const bf16x8*)&Bl[(((w * 2 + 0) * 4 + kt) * 64 + lane) * 8];
    bf16x8 b1 = *(const bf16x8*)&Bl[(((w * 2 + 1) * 4 + kt) * 64 + lane) * 8];
    int kb = kt * 32 + quad * 8;
#pragma unroll
    for (int rt = 0; rt < 8; ++rt) {
      int rr = mrow + rt * 16; if (rr > NN - 1) rr = NN - 1;
      bf16x8 a = *(const bf16x8*)&Abf[(size_t)rr * 128 + kb];
      acc[rt][0] = __builtin_amdgcn_mfma_f32_16x16x32_bf16(b0, a, acc[rt][0], 0, 0, 0);
      acc[rt][1] = __builtin_amdgcn_mfma_f32_16x16x32_bf16(b1, a, acc[rt][1], 0, 0, 0);
    }
  }
#pragma unroll
  for (int rt = 0; rt < 8; ++rt) {
    int m = row0 + rt * 16 + (lane & 15);
    if (m < NN) {
#pragma unroll
      for (int c = 0; c < 2; ++c) {
        int col = colbase + (w * 2 + c) * 16 + quad * 4;
        if (half == 0) {
          int pk = __builtin_amdgcn_cvt_pk_fp8_f32(acc[rt][c][0], acc[rt][c][1], 0, false);
          pk = __builtin_amdgcn_cvt_pk_fp8_f32(acc[rt][c][2], acc[rt][c][3], pk, true);
          feat8u[(size_t)m * 64 + (col >> 2)] = (unsigned)pk;
        } else {
          ushort4 o;
          o.x = f2b(acc[rt][c][0]); o.y = f2b(acc[rt][c][1]);
          o.z = f2b(acc[rt][c][2]); o.w = f2b(acc[rt][c][3]);
          *(ushort4*)&resval2[(size_t)m * 256 + col] = o;
        }
      }
    }
  }
}

// ---------------- res2_f32[N x 64] = relu(A[N x 128] * W_res^T + b_res) (fp32 VALU) ----------------
__global__ __launch_bounds__(256) void k_gemm_nt_bias_relu(const float* __restrict__ A, const float* __restrict__ B,
                                                           const float* __restrict__ bias, float* __restrict__ C) {
  __shared__ float Bl[128][68];
  for (int idx = threadIdx.x; idx < 64 * 128; idx += 256) {
    int d = idx >> 7, k = idx & 127;
    Bl[k][d] = B[d * 128 + k];
  }
  __syncthreads();
  int tx = threadIdx.x & 15, ty = threadIdx.x >> 4;
  int row0 = blockIdx.x * 64 + ty * 4;
  const float* ap[4];
#pragma unroll
  for (int r = 0; r < 4; ++r) ap[r] = A + (size_t)min(row0 + r, NN - 1) * 128;
  float4 acc[4];
#pragma unroll
  for (int r = 0; r < 4; ++r) acc[r] = make_float4(0.f, 0.f, 0.f, 0.f);
#pragma unroll 2
  for (int k0 = 0; k0 < 128; k0 += 4) {
    float4 b0 = *(const float4*)&Bl[k0][tx * 4];
    float4 b1 = *(const float4*)&Bl[k0 + 1][tx * 4];
    float4 b2 = *(const float4*)&Bl[k0 + 2][tx * 4];
    float4 b3 = *(const float4*)&Bl[k0 + 3][tx * 4];
#pragma unroll
    for (int r = 0; r < 4; ++r) {
      float4 a = *(const float4*)(ap[r] + k0);
      fma4(acc[r], a.x, b0); fma4(acc[r], a.y, b1);
      fma4(acc[r], a.z, b2); fma4(acc[r], a.w, b3);
    }
  }
  float4 bv = *(const float4*)&bias[tx * 4];
#pragma unroll
  for (int r = 0; r < 4; ++r) {
    int row = row0 + r;
    if (row < NN) {
      float4 v;
      v.x = fmaxf(acc[r].x + bv.x, 0.f);
      v.y = fmaxf(acc[r].y + bv.y, 0.f);
      v.z = fmaxf(acc[r].z + bv.z, 0.f);
      v.w = fmaxf(acc[r].w + bv.w, 0.f);
      *(float4*)&C[(size_t)row * 64 + tx * 4] = v;
    }
  }
}

// ---------------- fused edge-softmax + aggregation + relu + head-mix conv ----------------
// Restructured: 2 edges per wave-pass; lanes 0-31 -> edge A, 32-63 -> edge B.
// Each lane handles dims d0=2k, d0+1 (k=lane&31) via one dwordx2 fp8 load.
// Attention weights broadcast via LDS (ds_read_b128) instead of 4x v_readlane per edge.
__global__ __launch_bounds__(256) void k_gat(const int* __restrict__ row_start, const int* __restrict__ deg,
                                             const int* __restrict__ csr_src, const float* __restrict__ el,
                                             const float* __restrict__ er, const unsigned* __restrict__ feat8u,
                                             const unsigned short* __restrict__ resval2,
                                             const float* __restrict__ gat_bias, const float* __restrict__ conv_w,
                                             const float* __restrict__ conv_b, const float* __restrict__ nrm,
                                             float* __restrict__ h0, unsigned short* __restrict__ hsA) {
  __shared__ int s_src[4][64];
  __shared__ float s_x[4][64][4];
  int wid = threadIdx.x >> 6, lane = threadIdx.x & 63;
  int n = blockIdx.x * 4 + wid;
  if (n >= NN) return;
  int s0 = row_start[n], cnt = deg[n];
  float4 er4 = *(const float4*)&er[n * 4];
  int k = lane & 31, g = lane >> 5;
  unsigned koff = (unsigned)(k << 3);
  f32x2 a01_0 = (f32x2){0.f, 0.f}, a23_0 = (f32x2){0.f, 0.f};
  f32x2 a01_1 = (f32x2){0.f, 0.f}, a23_1 = (f32x2){0.f, 0.f};
  float den0 = 0.f, den1 = 0.f, den2 = 0.f, den3 = 0.f;
  for (int base = 0; base < cnt; base += 64) {
    int j = base + lane;
    int s = 0;
    float x0 = 0.f, x1 = 0.f, x2 = 0.f, x3 = 0.f;
    if (j < cnt) {
      s = csr_src[s0 + j];
      float4 el4 = *(const float4*)&el[s * 4];
      float e0 = el4.x + er4.x; e0 = (e0 > 0.f) ? e0 : NEG_SLOPE * e0;
      float e1 = el4.y + er4.y; e1 = (e1 > 0.f) ? e1 : NEG_SLOPE * e1;
      float e2 = el4.z + er4.z; e2 = (e2 > 0.f) ? e2 : NEG_SLOPE * e2;
      float e3 = el4.w + er4.w; e3 = (e3 > 0.f) ? e3 : NEG_SLOPE * e3;
      x0 = __expf(e0); x1 = __expf(e1); x2 = __expf(e2); x3 = __expf(e3);
      den0 += x0; den1 += x1; den2 += x2; den3 += x3;
    }
    s_src[wid][lane] = s;
    *(float4*)&s_x[wid][lane][0] = make_float4(x0, x1, x2, x3);
    int m = cnt - base; if (m > 64) m = 64;
    int mr = (m + 3) & ~3;
    for (int t = 0; t < mr; t += 4) {
      int sA = s_src[wid][t + g];
      int sB = s_src[wid][t + 2 + g];
      float4 xA = *(const float4*)&s_x[wid][t + g][0];
      float4 xB = *(const float4*)&s_x[wid][t + 2 + g][0];
      uint2 fA = *(const uint2*)((const char*)feat8u + (((unsigned)sA << 8) + koff));
      uint2 fB = *(const uint2*)((const char*)feat8u + (((unsigned)sB << 8) + koff));
      f32x2 xa01 = (f32x2){xA.x, xA.y}, xa23 = (f32x2){xA.z, xA.w};
      f32x2 xb01 = (f32x2){xB.x, xB.y}, xb23 = (f32x2){xB.z, xB.w};
      f32x2 lo, hi;
      lo = __builtin_amdgcn_cvt_pk_f32_fp8((int)fA.x, false);
      hi = __builtin_amdgcn_cvt_pk_f32_fp8((int)fA.x, true);
      a01_0 += xa01 * lo; a23_0 += xa23 * hi;
      lo = __builtin_amdgcn_cvt_pk_f32_fp8((int)fA.y, false);
      hi = __builtin_amdgcn_cvt_pk_f32_fp8((int)fA.y, true);
      a01_1 += xa01 * lo; a23_1 += xa23 * hi;
      lo = __builtin_amdgcn_cvt_pk_f32_fp8((int)fB.x, false);
      hi = __builtin_amdgcn_cvt_pk_f32_fp8((int)fB.x, true);
      a01_0 += xb01 * lo; a23_0 += xb23 * hi;
      lo = __builtin_amdgcn_cvt_pk_f32_fp8((int)fB.y, false);
      hi = __builtin_amdgcn_cvt_pk_f32_fp8((int)fB.y, true);
      a01_1 += xb01 * lo; a23_1 += xb23 * hi;
    }
  }
  den0 = wred(den0); den1 = wred(den1); den2 = wred(den2); den3 = wred(den3);
  float i0 = 1.f / fmaxf(den0, 1e-9f);
  float i1 = 1.f / fmaxf(den1, 1e-9f);
  float i2 = 1.f / fmaxf(den2, 1e-9f);
  float i3 = 1.f / fmaxf(den3, 1e-9f);
  a01_0[0] += __shfl_xor(a01_0[0], 32, 64);
  a01_0[1] += __shfl_xor(a01_0[1], 32, 64);
  a23_0[0] += __shfl_xor(a23_0[0], 32, 64);
  a23_0[1] += __shfl_xor(a23_0[1], 32, 64);
  a01_1[0] += __shfl_xor(a01_1[0], 32, 64);
  a01_1[1] += __shfl_xor(a01_1[1], 32, 64);
  a23_1[0] += __shfl_xor(a23_1[0], 32, 64);
  a23_1[1] += __shfl_xor(a23_1[1], 32, 64);
  if (lane < 32) {
    int d0 = k << 1;
    uint4 rv = *(const uint4*)&resval2[(size_t)n * 256 + ((unsigned)k << 3)];
    float2 bb0 = *(const float2*)&gat_bias[d0];
    float2 bb1 = *(const float2*)&gat_bias[64 + d0];
    float2 bb2 = *(const float2*)&gat_bias[128 + d0];
    float2 bb3 = *(const float2*)&gat_bias[192 + d0];
    float cb = conv_b[0];
    float cw0 = conv_w[0], cw1 = conv_w[1], cw2 = conv_w[2], cw3 = conv_w[3];
    float t, hm0 = cb, hm1 = cb;
    t = fmaf(a01_0[0], i0, b2f((unsigned short)(rv.x & 0xffffu)) + bb0.x); t = fmaxf(t, 0.f); hm0 = fmaf(cw0, t, hm0);
    t = fmaf(a01_0[1], i1, b2f((unsigned short)(rv.x >> 16)) + bb1.x);     t = fmaxf(t, 0.f); hm0 = fmaf(cw1, t, hm0);
    t = fmaf(a23_0[0], i2, b2f((unsigned short)(rv.y & 0xffffu)) + bb2.x); t = fmaxf(t, 0.f); hm0 = fmaf(cw2, t, hm0);
    t = fmaf(a23_0[1], i3, b2f((unsigned short)(rv.y >> 16)) + bb3.x);     t = fmaxf(t, 0.f); hm0 = fmaf(cw3, t, hm0);
    t = fmaf(a01_1[0], i0, b2f((unsigned short)(rv.z & 0xffffu)) + bb0.y); t = fmaxf(t, 0.f); hm1 = fmaf(cw0, t, hm1);
    t = fmaf(a01_1[1], i1, b2f((unsigned short)(rv.z >> 16)) + bb1.y);     t = fmaxf(t, 0.f); hm1 = fmaf(cw1, t, hm1);
    t = fmaf(a23_1[0], i2, b2f((unsigned short)(rv.w & 0xffffu)) + bb2.y); t = fmaxf(t, 0.f); hm1 = fmaf(cw2, t, hm1);
    t = fmaf(a23_1[1], i3, b2f((unsigned short)(rv.w >> 16)) + bb3.y);     t = fmaxf(t, 0.f); hm1 = fmaf(cw3, t, hm1);
    float nn_ = nrm[n];
    size_t o = (size_t)n * 64 + d0;
    *(float2*)&h0[o] = make_float2(hm0, hm1);
    ushort2 hs; hs.x = f2b(hm0 * nn_); hs.y = f2b(hm1 * nn_);
    *(ushort2*)&hsA[o] = hs;
  }
}

// ---------------- APPNP gather core: 4 edges per wave-pass, 16 lanes/edge, dwordx2 bf16 loads.
// After the loop, lanes 0-15 hold the fully-reduced dims 4k..4k+3.
__device__ __forceinline__ void gather_accum(const int* __restrict__ row_start, const int* __restrict__ deg,
                                             const int* __restrict__ csr_src,
                                             const unsigned short* __restrict__ hs_in,
                                             int n, int wid, int lane,
                                             float& a0, float& a1, float& a2, float& a3) {
  __shared__ int s_src[4][64];
  int s0 = row_start[n], cnt = deg[n];
  int k = lane & 15, g = lane >> 4;
  unsigned koff = (unsigned)(k << 3);
  a0 = 0.f; a1 = 0.f; a2 = 0.f; a3 = 0.f;
  for (int base = 0; base < cnt; base += 64) {
    int j = base + lane;
    s_src[wid][lane] = (j < cnt) ? csr_src[s0 + j] : NN;
    int m = cnt - base; if (m > 64) m = 64;
    int mr = (m + 7) & ~7;
    for (int t = 0; t < mr; t += 8) {
      int sA = s_src[wid][t + g];
      int sB = s_src[wid][t + 4 + g];
      uint2 uA = *(const uint2*)((const char*)hs_in + (((unsigned)sA << 7) + koff));
      uint2 uB = *(const uint2*)((const char*)hs_in + (((unsigned)sB << 7) + koff));
      a0 += __uint_as_float(uA.x << 16);
      a1 += __uint_as_float(uA.x & 0xFFFF0000u);
      a2 += __uint_as_float(uA.y << 16);
      a3 += __uint_as_float(uA.y & 0xFFFF0000u);
      a0 += __uint_as_float(uB.x << 16);
      a1 += __uint_as_float(uB.x & 0xFFFF0000u);
      a2 += __uint_as_float(uB.y << 16);
      a3 += __uint_as_float(uB.y & 0xFFFF0000u);
    }
  }
  a0 += __shfl_xor(a0, 16, 64); a1 += __shfl_xor(a1, 16, 64);
  a2 += __shfl_xor(a2, 16, 64); a3 += __shfl_xor(a3, 16, 64);
  a0 += __shfl_xor(a0, 32, 64); a1 += __shfl_xor(a1, 32, 64);
  a2 += __shfl_xor(a2, 32, 64); a3 += __shfl_xor(a3, 32, 64);
}

// ---------------- APPNP step (mid): hs_out = bf16(nrm[n]*(0.5*nrm[n]*sum hs_in[src] + 0.5*h0)) ----------------
__global__ __launch_bounds__(256) void k_gather_mid(const int* __restrict__ row_start, const int* __restrict__ deg,
                                                    const int* __restrict__ csr_src,
                                                    const unsigned short* __restrict__ hs_in,
                                                    const float* __restrict__ nrm, const float* __restrict__ h0,
                                                    unsigned short* __restrict__ hs_out) {
  int wid = threadIdx.x >> 6, lane = threadIdx.x & 63;
  int n = blockIdx.x * 4 + wid;
  if (n >= NN) return;
  float a0, a1, a2, a3;
  gather_accum(row_start, deg, csr_src, hs_in, n, wid, lane, a0, a1, a2, a3);
  if (lane < 16) {
    size_t o = (size_t)n * 64 + (lane << 2);
    float nn_ = nrm[n];
    float4 h4 = *(const float4*)&h0[o];
    float hn = 0.5f * nn_;
    float v0 = fmaf(hn, a0, 0.5f * h4.x) * nn_;
    float v1 = fmaf(hn, a1, 0.5f * h4.y) * nn_;
    float v2 = fmaf(hn, a2, 0.5f * h4.z) * nn_;
    float v3 = fmaf(hn, a3, 0.5f * h4.w) * nn_;
    ushort4 ov; ov.x = f2b(v0); ov.y = f2b(v1); ov.z = f2b(v2); ov.w = f2b(v3);
    *(ushort4*)&hs_out[o] = ov;
  }
}

// ---------------- APPNP step (last) fused with final residual add: h0io = appnp + res2 (f32) ----------------
__global__ __launch_bounds__(256) void k_gather_last(const int* __restrict__ row_start, const int* __restrict__ deg,
                                                     const int* __restrict__ csr_src,
                                                     const unsigned short* __restrict__ hs_in,
                                                     const float* __restrict__ nrm,
                                                     const float* __restrict__ res2,
                                                     float* h0io) {
  int wid = threadIdx.x >> 6, lane = threadIdx.x & 63;
  int n = blockIdx.x * 4 + wid;
  if (n >= NN) return;
  float a0, a1, a2, a3;
  gather_accum(row_start, deg, csr_src, hs_in, n, wid, lane, a0, a1, a2, a3);
  if (lane < 16) {
    size_t o = (size_t)n * 64 + (lane << 2);
    float nn_ = nrm[n];
    float4 h4 = *(const float4*)&h0io[o];
    float4 r4 = *(const float4*)&res2[o];
    float hn = 0.5f * nn_;
    float4 v;
    v.x = fmaf(hn, a0, 0.5f * h4.x) + r4.x;
    v.y = fmaf(hn, a1, 0.5f * h4.y) + r4.y;
    v.z = fmaf(hn, a2, 0.5f * h4.z) + r4.z;
    v.w = fmaf(hn, a3, 0.5f * h4.w) + r4.w;
    *(float4*)&h0io[o] = v;
  }
}

// ---------------- BN partial sums (pure reduction over hfin f32) ----------------
__global__ __launch_bounds__(256) void k_finred(const float* __restrict__ hfin, float* __restrict__ bn) {
  __shared__ float s1[256], s2[256];
  int d = threadIdx.x & 63;
  int rb = blockIdx.x * 64;
  float sum = 0.f, sq = 0.f;
  for (int r = threadIdx.x >> 6; r < 64; r += 4) {
    int n = rb + r;
    if (n < NN) {
      float v = hfin[(size_t)n * 64 + d];
      sum += v; sq += v * v;
    }
  }
  s1[threadIdx.x] = sum; s2[threadIdx.x] = sq;
  __syncthreads();
  if (threadIdx.x < 128) { s1[threadIdx.x] += s1[threadIdx.x + 128]; s2[threadIdx.x] += s2[threadIdx.x + 128]; }
  __syncthreads();
  if (threadIdx.x < 64) {
    atomicAdd(&bn[d], s1[threadIdx.x] + s1[threadIdx.x + 64]);
    atomicAdd(&bn[64 + d], s2[threadIdx.x] + s2[threadIdx.x + 64]);
  }
}

__global__ void k_bnstats(const float* __restrict__ bn, const float* __restrict__ gamma,
                          const float* __restrict__ beta, float* __restrict__ bns) {
  int d = threadIdx.x;
  float mu = bn[d] * (1.0f / NN);
  float var = fmaxf(bn[64 + d] * (1.0f / NN) - mu * mu, 0.f);
  float sc = rsqrtf(var + 1e-5f) * gamma[d];
  bns[d] = sc;
  bns[64 + d] = beta[d] - mu * sc;
}

__global__ __launch_bounds__(256) void k_bnapply(const float* __restrict__ h, const float* __restrict__ bns,
                                                 float* __restrict__ out) {
  int i = blockIdx.x * 256 + threadIdx.x;
  if (i < NN * 64) {
    int d = i & 63;
    out[i] = fmaf(h[i], bns[d], bns[64 + d]);
  }
}

extern "C" void kernel_launch(void* const* d_in, const int* in_sizes, int n_in,
                              void* d_out, int out_size, void* d_ws, size_t ws_size,
                              hipStream_t stream) {
  const float* node_feats = (const float*)d_in[0];
  const int* src = (const int*)d_in[1];
  const int* dst = (const int*)d_in[2];
  const float* W_fc = (const float*)d_in[3];
  const float* attn_l = (const float*)d_in[4];
  const float* attn_r = (const float*)d_in[5];
  const float* W_res_gat = (const float*)d_in[6];
  const float* gat_bias = (const float*)d_in[7];
  const float* conv_w = (const float*)d_in[8];
  const float* conv_b = (const float*)d_in[9];
  const float* W_res = (const float*)d_in[10];
  const float* b_res = (const float*)d_in[11];
  const float* gamma = (const float*)d_in[12];
  const float* beta = (const float*)d_in[13];
  float* out = (float*)d_out;

  char* base = (char*)d_ws;
  size_t off = 0;
  auto alloc = [&](size_t bytes) -> char* {
    char* p = base + off;
    off = (off + bytes + 255) & ~(size_t)255;
    return p;
  };
  unsigned* feat8u        = (unsigned*)alloc((size_t)NN * 256);                  // 25.6 MB fp8 (n,d,h)
  unsigned short* resval2 = (unsigned short*)alloc((size_t)NN * 256 * 2);        // 51.2 MB bf16; res2 f32 aliases after k_gat
  float* res2             = (float*)resval2;
  float* el               = (float*)alloc((size_t)NN * 4 * 4);
  float* er               = (float*)alloc((size_t)NN * 4 * 4);
  float* h0               = (float*)alloc((size_t)NN * 64 * 4);                  // 25.6 MB; Abf aliases BEFORE k_gat; hfin at end
  unsigned short* Abf     = (unsigned short*)h0;
  unsigned short* hsA     = (unsigned short*)alloc((size_t)(NN + 1) * 64 * 2);   // 12.8 MB bf16 + dummy row
  unsigned short* hsB     = (unsigned short*)alloc((size_t)(NN + 1) * 64 * 2);
  int* csr_src            = (int*)alloc((size_t)NE * 4);
  float* nrm              = (float*)alloc((size_t)NN * 4);
  int* row_start          = (int*)alloc((size_t)NN * 4);
  unsigned short* Bpacked = (unsigned short*)alloc((size_t)4 * 16384 * 2);
  float* w_elr            = (float*)alloc((size_t)8 * 128 * 4);
  size_t zoff = off;
  int* deg                = (int*)alloc((size_t)NN * 4);
  int* cursor             = (int*)alloc((size_t)NN * 4);
  int* counter            = (int*)alloc(256);
  float* bn               = (float*)alloc(256 * 4);
  float* hfin             = h0;

  int zwords = (int)((off - zoff) / 4);
  int gE = (NE + 255) / 256;
  int gN = (NN + 255) / 256;
  int gW = (NN + 3) / 4;
  int gM = (NN + 63) / 64;
  int gV = (NN * 64 + 255) / 256;

  k_zero<<<(zwords + 255) / 256, 256, 0, stream>>>((int*)(base + zoff), zwords);
  k_zrow<<<1, 64, 0, stream>>>(hsA, hsB);
  k_deg<<<gE, 256, 0, stream>>>(dst, deg);
  k_alloc<<<gN, 256, 0, stream>>>(deg, row_start, counter, nrm);
  k_scatter<<<gE, 256, 0, stream>>>(src, dst, row_start, cursor, csr_src);

  k_cast<<<(NN * 128 / 4 + 255) / 256, 256, 0, stream>>>(node_feats, Abf);
  k_prepB<<<dim3(8, 4), 256, 0, stream>>>(W_fc, W_res_gat, Bpacked);
  k_prepw<<<4, 256, 0, stream>>>(W_fc, attn_l, attn_r, w_elr);
  k_gemm_mfma<<<dim3((NN + 127) / 128, 4), 256, 0, stream>>>(Abf, Bpacked, feat8u, resval2);

  k_elr2<<<(NN + 31) / 32, 256, 0, stream>>>(node_feats, w_elr, el, er);
  k_gat<<<gW, 256, 0, stream>>>(row_start, deg, csr_src, el, er, feat8u, resval2,
                                gat_bias, conv_w, conv_b, nrm, h0, hsA);

  // resval2 dead now; res2 (f32) reuses its space
  k_gemm_nt_bias_relu<<<gM, 256, 0, stream>>>(node_feats, W_res, b_res, res2);

  k_gather_mid<<<gW, 256, 0, stream>>>(row_start, deg, csr_src, hsA, nrm, h0, hsB);
  k_gather_mid<<<gW, 256, 0, stream>>>(row_start, deg, csr_src, hsB, nrm, h0, hsA);
  k_gather_mid<<<gW, 256, 0, stream>>>(row_start, deg, csr_src, hsA, nrm, h0, hsB);
  k_gather_mid<<<gW, 256, 0, stream>>>(row_start, deg, csr_src, hsB, nrm, h0, hsA);
  // last step fused with residual add: writes hfin (= h0) in f32
  k_gather_last<<<gW, 256, 0, stream>>>(row_start, deg, csr_src, hsA, nrm, res2, hfin);

  k_finred<<<gM, 256, 0, stream>>>(hfin, bn);
  k_bnstats<<<1, 64, 0, stream>>>(bn, gamma, beta, bn + 128);
  k_bnapply<<<gV, 256, 0, stream>>>(hfin, bn + 128, out);
}

// Round 2
// 781.405 us; speedup vs baseline: 1.0769x; 1.0685x over previous
//
#include <hip/hip_runtime.h>
#include <math.h>

#define NN 100000
#define NE 1600000
#define NEG_SLOPE 0.2f

typedef __attribute__((ext_vector_type(8))) short bf16x8;
typedef __attribute__((ext_vector_type(4))) float f32x4;
typedef __attribute__((ext_vector_type(2))) float f32x2;

__device__ __forceinline__ float b2f(unsigned short u) {
  union { unsigned u; float f; } c; c.u = ((unsigned)u) << 16; return c.f;
}
__device__ __forceinline__ unsigned short f2b(float x) {
  union { float f; unsigned u; } c; c.f = x;
  unsigned r = c.u + 0x7FFFu + ((c.u >> 16) & 1u);
  return (unsigned short)(r >> 16);
}
__device__ __forceinline__ void fma4(float4& acc, float s, const float4& b) {
  acc.x = fmaf(s, b.x, acc.x);
  acc.y = fmaf(s, b.y, acc.y);
  acc.z = fmaf(s, b.z, acc.z);
  acc.w = fmaf(s, b.w, acc.w);
}

// ---------------- utility ----------------
__global__ __launch_bounds__(256) void k_zero(int* __restrict__ p, int nwords) {
  int i = blockIdx.x * 256 + threadIdx.x;
  if (i < nwords) p[i] = 0;
}

// zero the dummy rows (index NN) of the bf16 ping-pong buffers
__global__ void k_zrow(unsigned short* __restrict__ a, unsigned short* __restrict__ b) {
  int i = threadIdx.x;
  a[(size_t)NN * 64 + i] = 0;
  b[(size_t)NN * 64 + i] = 0;
}

__global__ __launch_bounds__(256) void k_cast(const float* __restrict__ A, unsigned short* __restrict__ Ab) {
  int i = blockIdx.x * 256 + threadIdx.x;
  int i4 = i * 4;
  if (i4 < NN * 128) {
    float4 v = *(const float4*)&A[i4];
    ushort4 o; o.x = f2b(v.x); o.y = f2b(v.y); o.z = f2b(v.z); o.w = f2b(v.w);
    *(ushort4*)&Ab[i4] = o;
  }
}

// ---------------- CSR build (unordered within row) ----------------
__global__ __launch_bounds__(256) void k_deg(const int* __restrict__ dst, int* __restrict__ deg) {
  int i = blockIdx.x * 256 + threadIdx.x;
  if (i < NE) atomicAdd(&deg[dst[i]], 1);
}

__global__ __launch_bounds__(256) void k_alloc(const int* __restrict__ deg, int* __restrict__ row_start,
                                               int* __restrict__ counter, float* __restrict__ nrm) {
  int i = blockIdx.x * 256 + threadIdx.x;
  if (i < NN) {
    row_start[i] = atomicAdd(counter, deg[i]);
    nrm[i] = rsqrtf(fmaxf((float)deg[i], 1.0f));
  }
}

__global__ __launch_bounds__(256) void k_scatter(const int* __restrict__ src, const int* __restrict__ dst,
                                                 const int* __restrict__ row_start, int* __restrict__ cursor,
                                                 int* __restrict__ csr_src) {
  int i = blockIdx.x * 256 + threadIdx.x;
  if (i < NE) {
    int n = dst[i];
    int p = atomicAdd(&cursor[n], 1);
    csr_src[row_start[n] + p] = src[i];
  }
}

// ---------------- fold attention vectors into W_fc: w[p][k], p = side*4+h ----------------
__global__ __launch_bounds__(256) void k_prepw(const float* __restrict__ W_fc, const float* __restrict__ al,
                                               const float* __restrict__ ar, float* __restrict__ w) {
  int o = blockIdx.x * 256 + threadIdx.x;  // [0,1024)
  if (o >= 1024) return;
  int side = o >> 9;
  int h = (o >> 7) & 3;
  int k = o & 127;
  const float* a = side ? ar : al;
  float s = 0.f;
  for (int d = 0; d < 64; ++d) s += W_fc[k * 256 + h * 64 + d] * a[h * 64 + d];
  w[(side * 4 + h) * 128 + k] = s;
}

// ---------------- exact el/er GEMV: thread = (node, p) ----------------
__global__ __launch_bounds__(256) void k_elr2(const float* __restrict__ X, const float* __restrict__ w,
                                              float* __restrict__ el, float* __restrict__ er) {
  int n = blockIdx.x * 32 + (threadIdx.x >> 3);
  int p = threadIdx.x & 7;
  if (n >= NN) return;
  const float4* xr = (const float4*)(X + (size_t)n * 128);
  const float4* wr = (const float4*)(w + p * 128);
  float s = 0.f;
#pragma unroll
  for (int i = 0; i < 32; ++i) {
    float4 x = xr[i], ww = wr[i];
    s += x.x * ww.x + x.y * ww.y + x.z * ww.z + x.w * ww.w;
  }
  if (p < 4) el[n * 4 + p] = s;
  else er[n * 4 + (p - 4)] = s;
}

// ---------------- pre-pack B (both weight mats) into MFMA fragment order ----------------
// layout: [y][kt][nt][quad*16+nn][j]  (kt outer so each kt-pair half is contiguous 16 KB)
__global__ __launch_bounds__(256) void k_prepB(const float* __restrict__ W_fc, const float* __restrict__ W_rg,
                                               unsigned short* __restrict__ Bp) {
  int y = blockIdx.y;
  const float* Bsrc = (y >> 1) ? W_rg : W_fc;
  int colbase = (y & 1) * 128;
  for (int e = blockIdx.x * 256 + threadIdx.x; e < 16384; e += 2048) {
    int n = e & 127, k = e >> 7;
    int p = colbase + n;
    int d = p >> 2, hh = p & 3;
    float v = Bsrc[k * 256 + hh * 64 + d];
    int nt = n >> 4, nn = n & 15, kt = k >> 5, quad = (k >> 3) & 3, j = k & 7;
    Bp[(size_t)y * 16384 + ((kt * 8 + nt) * 64 + quad * 16 + nn) * 8 + j] = f2b(v);
  }
}

// ---------------- merged bf16 MFMA GEMM (LDS-staged A, coalesced epilogue) ----------------
// y=0,1 -> feat8 (fp8, (n,d,h) interleaved); y=2,3 -> resval2 (bf16 interleaved)
__global__ __launch_bounds__(256) void k_gemm_mfma(const unsigned short* __restrict__ Abf,
                                                   const unsigned short* __restrict__ Bp,
                                                   unsigned* __restrict__ feat8u,
                                                   unsigned short* __restrict__ resval2) {
  __shared__ unsigned short Al[128 * 136];  // A tile, 272-B row stride (pad kills bank conflicts)
  __shared__ unsigned short Bl[8192];       // B kt-pair half (16 KB)
  int tid = threadIdx.x;
  int half = blockIdx.y >> 1;
  int colbase = (blockIdx.y & 1) * 128;
  int row0 = blockIdx.x * 128;
  // stage A: 2048 chunks of 16 B, fully coalesced
#pragma unroll
  for (int i = 0; i < 8; ++i) {
    int c = tid + i * 256;
    int row = c >> 4, part = c & 15;
    int gr = row0 + row; if (gr > NN - 1) gr = NN - 1;
    *(uint4*)&Al[row * 136 + part * 8] = *(const uint4*)&Abf[(size_t)gr * 128 + part * 8];
  }
  // stage B half 0 (kt = 0,1)
  {
    const uint4* srcb = (const uint4*)(Bp + (size_t)blockIdx.y * 16384);
    uint4* dst4 = (uint4*)Bl;
#pragma unroll
    for (int i = 0; i < 4; ++i) dst4[tid + i * 256] = srcb[tid + i * 256];
  }
  __syncthreads();
  int w = tid >> 6, lane = tid & 63;
  int quad = lane >> 4, l16 = lane & 15;
  f32x4 acc[8][2];
#pragma unroll
  for (int rt = 0; rt < 8; ++rt)
#pragma unroll
    for (int c = 0; c < 2; ++c) acc[rt][c] = (f32x4){0.f, 0.f, 0.f, 0.f};
#pragma unroll
  for (int kh = 0; kh < 2; ++kh) {
    if (kh == 1) {
      __syncthreads();  // everyone done reading B half 0
      const uint4* srcb = (const uint4*)(Bp + (size_t)blockIdx.y * 16384 + 8192);
      uint4* dst4 = (uint4*)Bl;
#pragma unroll
      for (int i = 0; i < 4; ++i) dst4[tid + i * 256] = srcb[tid + i * 256];
      __syncthreads();
    }
#pragma unroll
    for (int ktl = 0; ktl < 2; ++ktl) {
      int kt = kh * 2 + ktl;
      bf16x8 b0 = *(const bf16x8*)&Bl[((ktl * 8 + w * 2 + 0) * 64 + lane) * 8];
      bf16x8 b1 = *(const bf16x8*)&Bl[((ktl * 8 + w * 2 + 1) * 64 + lane) * 8];
      int kb = kt * 32 + quad * 8;
#pragma unroll
      for (int rt = 0; rt < 8; ++rt) {
        bf16x8 a = *(const bf16x8*)&Al[(rt * 16 + l16) * 136 + kb];
        acc[rt][0] = __builtin_amdgcn_mfma_f32_16x16x32_bf16(b0, a, acc[rt][0], 0, 0, 0);
        acc[rt][1] = __builtin_amdgcn_mfma_f32_16x16x32_bf16(b1, a, acc[rt][1], 0, 0, 0);
      }
    }
  }
  __syncthreads();  // Al/Bl reads done; reuse Al for epilogue staging
  if (half == 0) {
    unsigned* Cl = (unsigned*)Al;  // [128][36] dwords (pad 32->36)
#pragma unroll
    for (int rt = 0; rt < 8; ++rt)
#pragma unroll
      for (int c = 0; c < 2; ++c) {
        int pk = __builtin_amdgcn_cvt_pk_fp8_f32(acc[rt][c][0], acc[rt][c][1], 0, false);
        pk = __builtin_amdgcn_cvt_pk_fp8_f32(acc[rt][c][2], acc[rt][c][3], pk, true);
        Cl[(rt * 16 + l16) * 36 + (w * 2 + c) * 4 + quad] = (unsigned)pk;
      }
    __syncthreads();
#pragma unroll
    for (int i = 0; i < 4; ++i) {
      int c = tid + i * 256;        // 1024 chunks: 128 rows x 8 uint4
      int row = c >> 3, wp = c & 7;
      int m = row0 + row;
      if (m < NN)
        *(uint4*)&feat8u[(size_t)m * 64 + (colbase >> 2) + wp * 4] = *(const uint4*)&Cl[row * 36 + wp * 4];
    }
  } else {
#pragma unroll
    for (int rt = 0; rt < 8; ++rt)
#pragma unroll
      for (int c = 0; c < 2; ++c) {
        int col = (w * 2 + c) * 16 + quad * 4;
        ushort4 o;
        o.x = f2b(acc[rt][c][0]); o.y = f2b(acc[rt][c][1]);
        o.z = f2b(acc[rt][c][2]); o.w = f2b(acc[rt][c][3]);
        *(ushort4*)&Al[(rt * 16 + l16) * 136 + col] = o;
      }
    __syncthreads();
#pragma unroll
    for (int i = 0; i < 8; ++i) {
      int c = tid + i * 256;        // 2048 chunks: 128 rows x 16 uint4
      int row = c >> 4, part = c & 15;
      int m = row0 + row;
      if (m < NN)
        *(uint4*)&resval2[(size_t)m * 256 + colbase + part * 8] = *(const uint4*)&Al[row * 136 + part * 8];
    }
  }
}

// ---------------- res2_f32[N x 64] = relu(A[N x 128] * W_res^T + b_res) (fp32 VALU) ----------------
__global__ __launch_bounds__(256) void k_gemm_nt_bias_relu(const float* __restrict__ A, const float* __restrict__ B,
                                                           const float* __restrict__ bias, float* __restrict__ C) {
  __shared__ float Bl[128][68];
  for (int idx = threadIdx.x; idx < 64 * 128; idx += 256) {
    int d = idx >> 7, k = idx & 127;
    Bl[k][d] = B[d * 128 + k];
  }
  __syncthreads();
  int tx = threadIdx.x & 15, ty = threadIdx.x >> 4;
  int row0 = blockIdx.x * 64 + ty * 4;
  const float* ap[4];
#pragma unroll
  for (int r = 0; r < 4; ++r) ap[r] = A + (size_t)min(row0 + r, NN - 1) * 128;
  float4 acc[4];
#pragma unroll
  for (int r = 0; r < 4; ++r) acc[r] = make_float4(0.f, 0.f, 0.f, 0.f);
#pragma unroll 2
  for (int k0 = 0; k0 < 128; k0 += 4) {
    float4 b0 = *(const float4*)&Bl[k0][tx * 4];
    float4 b1 = *(const float4*)&Bl[k0 + 1][tx * 4];
    float4 b2 = *(const float4*)&Bl[k0 + 2][tx * 4];
    float4 b3 = *(const float4*)&Bl[k0 + 3][tx * 4];
#pragma unroll
    for (int r = 0; r < 4; ++r) {
      float4 a = *(const float4*)(ap[r] + k0);
      fma4(acc[r], a.x, b0); fma4(acc[r], a.y, b1);
      fma4(acc[r], a.z, b2); fma4(acc[r], a.w, b3);
    }
  }
  float4 bv = *(const float4*)&bias[tx * 4];
#pragma unroll
  for (int r = 0; r < 4; ++r) {
    int row = row0 + r;
    if (row < NN) {
      float4 v;
      v.x = fmaxf(acc[r].x + bv.x, 0.f);
      v.y = fmaxf(acc[r].y + bv.y, 0.f);
      v.z = fmaxf(acc[r].z + bv.z, 0.f);
      v.w = fmaxf(acc[r].w + bv.w, 0.f);
      *(float4*)&C[(size_t)row * 64 + tx * 4] = v;
    }
  }
}

// ---------------- fused edge-softmax + aggregation + relu + head-mix conv ----------------
// 2 edge-pairs per wave-pass; lanes 0-31 -> edge slots t+0/t+2, lanes 32-63 -> t+1/t+3.
// den accumulated in phase 2 as packed partials (each half sees a disjoint half of edges).
__global__ __launch_bounds__(256) void k_gat(const int* __restrict__ row_start, const int* __restrict__ deg,
                                             const int* __restrict__ csr_src, const float* __restrict__ el,
                                             const float* __restrict__ er, const unsigned* __restrict__ feat8u,
                                             const unsigned short* __restrict__ resval2,
                                             const float* __restrict__ gat_bias, const float* __restrict__ conv_w,
                                             const float* __restrict__ conv_b, const float* __restrict__ nrm,
                                             float* __restrict__ h0, unsigned short* __restrict__ hsA) {
  __shared__ int s_src[4][64];
  __shared__ float s_x[4][64][4];
  int wid = threadIdx.x >> 6, lane = threadIdx.x & 63;
  int n = blockIdx.x * 4 + wid;
  if (n >= NN) return;
  int s0 = row_start[n], cnt = deg[n];
  float4 er4 = *(const float4*)&er[n * 4];
  int k = lane & 31, g = lane >> 5;
  unsigned koff = (unsigned)(k << 3);
  f32x2 a01_0 = (f32x2){0.f, 0.f}, a23_0 = (f32x2){0.f, 0.f};
  f32x2 a01_1 = (f32x2){0.f, 0.f}, a23_1 = (f32x2){0.f, 0.f};
  f32x2 den01 = (f32x2){0.f, 0.f}, den23 = (f32x2){0.f, 0.f};
  for (int base = 0; base < cnt; base += 64) {
    int j = base + lane;
    int s = 0;
    float x0 = 0.f, x1 = 0.f, x2 = 0.f, x3 = 0.f;
    if (j < cnt) {
      s = csr_src[s0 + j];
      float4 el4 = *(const float4*)&el[s * 4];
      float e0 = el4.x + er4.x; e0 = (e0 > 0.f) ? e0 : NEG_SLOPE * e0;
      float e1 = el4.y + er4.y; e1 = (e1 > 0.f) ? e1 : NEG_SLOPE * e1;
      float e2 = el4.z + er4.z; e2 = (e2 > 0.f) ? e2 : NEG_SLOPE * e2;
      float e3 = el4.w + er4.w; e3 = (e3 > 0.f) ? e3 : NEG_SLOPE * e3;
      x0 = __expf(e0); x1 = __expf(e1); x2 = __expf(e2); x3 = __expf(e3);
    }
    s_src[wid][lane] = s;
    *(float4*)&s_x[wid][lane][0] = make_float4(x0, x1, x2, x3);
    int m = cnt - base; if (m > 64) m = 64;
    int mr = (m + 3) & ~3;
    for (int t = 0; t < mr; t += 4) {
      int sA = s_src[wid][t + g];
      int sB = s_src[wid][t + 2 + g];
      float4 xA = *(const float4*)&s_x[wid][t + g][0];
      float4 xB = *(const float4*)&s_x[wid][t + 2 + g][0];
      uint2 fA = *(const uint2*)((const char*)feat8u + (((unsigned)sA << 8) + koff));
      uint2 fB = *(const uint2*)((const char*)feat8u + (((unsigned)sB << 8) + koff));
      f32x2 xa01 = (f32x2){xA.x, xA.y}, xa23 = (f32x2){xA.z, xA.w};
      f32x2 xb01 = (f32x2){xB.x, xB.y}, xb23 = (f32x2){xB.z, xB.w};
      den01 += xa01; den01 += xb01;
      den23 += xa23; den23 += xb23;
      f32x2 lo, hi;
      lo = __builtin_amdgcn_cvt_pk_f32_fp8((int)fA.x, false);
      hi = __builtin_amdgcn_cvt_pk_f32_fp8((int)fA.x, true);
      a01_0 += xa01 * lo; a23_0 += xa23 * hi;
      lo = __builtin_amdgcn_cvt_pk_f32_fp8((int)fA.y, false);
      hi = __builtin_amdgcn_cvt_pk_f32_fp8((int)fA.y, true);
      a01_1 += xa01 * lo; a23_1 += xa23 * hi;
      lo = __builtin_amdgcn_cvt_pk_f32_fp8((int)fB.x, false);
      hi = __builtin_amdgcn_cvt_pk_f32_fp8((int)fB.x, true);
      a01_0 += xb01 * lo; a23_0 += xb23 * hi;
      lo = __builtin_amdgcn_cvt_pk_f32_fp8((int)fB.y, false);
      hi = __builtin_amdgcn_cvt_pk_f32_fp8((int)fB.y, true);
      a01_1 += xb01 * lo; a23_1 += xb23 * hi;
    }
  }
  // den: halves g=0/g=1 saw disjoint edge sets; one xor-32 completes the reduction
  den01[0] += __shfl_xor(den01[0], 32, 64);
  den01[1] += __shfl_xor(den01[1], 32, 64);
  den23[0] += __shfl_xor(den23[0], 32, 64);
  den23[1] += __shfl_xor(den23[1], 32, 64);
  float i0 = 1.f / fmaxf(den01[0], 1e-9f);
  float i1 = 1.f / fmaxf(den01[1], 1e-9f);
  float i2 = 1.f / fmaxf(den23[0], 1e-9f);
  float i3 = 1.f / fmaxf(den23[1], 1e-9f);
  a01_0[0] += __shfl_xor(a01_0[0], 32, 64);
  a01_0[1] += __shfl_xor(a01_0[1], 32, 64);
  a23_0[0] += __shfl_xor(a23_0[0], 32, 64);
  a23_0[1] += __shfl_xor(a23_0[1], 32, 64);
  a01_1[0] += __shfl_xor(a01_1[0], 32, 64);
  a01_1[1] += __shfl_xor(a01_1[1], 32, 64);
  a23_1[0] += __shfl_xor(a23_1[0], 32, 64);
  a23_1[1] += __shfl_xor(a23_1[1], 32, 64);
  if (lane < 32) {
    int d0 = k << 1;
    uint4 rv = *(const uint4*)&resval2[(size_t)n * 256 + ((unsigned)k << 3)];
    float2 bb0 = *(const float2*)&gat_bias[d0];
    float2 bb1 = *(const float2*)&gat_bias[64 + d0];
    float2 bb2 = *(const float2*)&gat_bias[128 + d0];
    float2 bb3 = *(const float2*)&gat_bias[192 + d0];
    float cb = conv_b[0];
    float cw0 = conv_w[0], cw1 = conv_w[1], cw2 = conv_w[2], cw3 = conv_w[3];
    float t, hm0 = cb, hm1 = cb;
    t = fmaf(a01_0[0], i0, b2f((unsigned short)(rv.x & 0xffffu)) + bb0.x); t = fmaxf(t, 0.f); hm0 = fmaf(cw0, t, hm0);
    t = fmaf(a01_0[1], i1, b2f((unsigned short)(rv.x >> 16)) + bb1.x);     t = fmaxf(t, 0.f); hm0 = fmaf(cw1, t, hm0);
    t = fmaf(a23_0[0], i2, b2f((unsigned short)(rv.y & 0xffffu)) + bb2.x); t = fmaxf(t, 0.f); hm0 = fmaf(cw2, t, hm0);
    t = fmaf(a23_0[1], i3, b2f((unsigned short)(rv.y >> 16)) + bb3.x);     t = fmaxf(t, 0.f); hm0 = fmaf(cw3, t, hm0);
    t = fmaf(a01_1[0], i0, b2f((unsigned short)(rv.z & 0xffffu)) + bb0.y); t = fmaxf(t, 0.f); hm1 = fmaf(cw0, t, hm1);
    t = fmaf(a01_1[1], i1, b2f((unsigned short)(rv.z >> 16)) + bb1.y);     t = fmaxf(t, 0.f); hm1 = fmaf(cw1, t, hm1);
    t = fmaf(a23_1[0], i2, b2f((unsigned short)(rv.w & 0xffffu)) + bb2.y); t = fmaxf(t, 0.f); hm1 = fmaf(cw2, t, hm1);
    t = fmaf(a23_1[1], i3, b2f((unsigned short)(rv.w >> 16)) + bb3.y);     t = fmaxf(t, 0.f); hm1 = fmaf(cw3, t, hm1);
    float nn_ = nrm[n];
    size_t o = (size_t)n * 64 + d0;
    *(float2*)&h0[o] = make_float2(hm0, hm1);
    ushort2 hs; hs.x = f2b(hm0 * nn_); hs.y = f2b(hm1 * nn_);
    *(ushort2*)&hsA[o] = hs;
  }
}

// ---------------- APPNP gather core: 4 edges per wave-pass, 16 lanes/edge, dwordx2 bf16 loads.
// After the loop, lanes 0-15 hold the fully-reduced dims 4k..4k+3.
__device__ __forceinline__ void gather_accum(const int* __restrict__ row_start, const int* __restrict__ deg,
                                             const int* __restrict__ csr_src,
                                             const unsigned short* __restrict__ hs_in,
                                             int n, int wid, int lane,
                                             float& a0, float& a1, float& a2, float& a3) {
  __shared__ int s_src[4][64];
  int s0 = row_start[n], cnt = deg[n];
  int k = lane & 15, g = lane >> 4;
  unsigned koff = (unsigned)(k << 3);
  a0 = 0.f; a1 = 0.f; a2 = 0.f; a3 = 0.f;
  for (int base = 0; base < cnt; base += 64) {
    int j = base + lane;
    s_src[wid][lane] = (j < cnt) ? csr_src[s0 + j] : NN;
    int m = cnt - base; if (m > 64) m = 64;
    int mr = (m + 7) & ~7;
    for (int t = 0; t < mr; t += 8) {
      int sA = s_src[wid][t + g];
      int sB = s_src[wid][t + 4 + g];
      uint2 uA = *(const uint2*)((const char*)hs_in + (((unsigned)sA << 7) + koff));
      uint2 uB = *(const uint2*)((const char*)hs_in + (((unsigned)sB << 7) + koff));
      a0 += __uint_as_float(uA.x << 16);
      a1 += __uint_as_float(uA.x & 0xFFFF0000u);
      a2 += __uint_as_float(uA.y << 16);
      a3 += __uint_as_float(uA.y & 0xFFFF0000u);
      a0 += __uint_as_float(uB.x << 16);
      a1 += __uint_as_float(uB.x & 0xFFFF0000u);
      a2 += __uint_as_float(uB.y << 16);
      a3 += __uint_as_float(uB.y & 0xFFFF0000u);
    }
  }
  a0 += __shfl_xor(a0, 16, 64); a1 += __shfl_xor(a1, 16, 64);
  a2 += __shfl_xor(a2, 16, 64); a3 += __shfl_xor(a3, 16, 64);
  a0 += __shfl_xor(a0, 32, 64); a1 += __shfl_xor(a1, 32, 64);
  a2 += __shfl_xor(a2, 32, 64); a3 += __shfl_xor(a3, 32, 64);
}

// ---------------- APPNP step (mid): hs_out = bf16(nrm[n]*(0.5*nrm[n]*sum hs_in[src] + 0.5*h0)) ----------------
__global__ __launch_bounds__(256) void k_gather_mid(const int* __restrict__ row_start, const int* __restrict__ deg,
                                                    const int* __restrict__ csr_src,
                                                    const unsigned short* __restrict__ hs_in,
                                                    const float* __restrict__ nrm, const float* __restrict__ h0,
                                                    unsigned short* __restrict__ hs_out) {
  int wid = threadIdx.x >> 6, lane = threadIdx.x & 63;
  int n = blockIdx.x * 4 + wid;
  if (n >= NN) return;
  float a0, a1, a2, a3;
  gather_accum(row_start, deg, csr_src, hs_in, n, wid, lane, a0, a1, a2, a3);
  if (lane < 16) {
    size_t o = (size_t)n * 64 + (lane << 2);
    float nn_ = nrm[n];
    float4 h4 = *(const float4*)&h0[o];
    float hn = 0.5f * nn_;
    float v0 = fmaf(hn, a0, 0.5f * h4.x) * nn_;
    float v1 = fmaf(hn, a1, 0.5f * h4.y) * nn_;
    float v2 = fmaf(hn, a2, 0.5f * h4.z) * nn_;
    float v3 = fmaf(hn, a3, 0.5f * h4.w) * nn_;
    ushort4 ov; ov.x = f2b(v0); ov.y = f2b(v1); ov.z = f2b(v2); ov.w = f2b(v3);
    *(ushort4*)&hs_out[o] = ov;
  }
}

// ---------------- APPNP step (last) fused with final residual add: h0io = appnp + res2 (f32) ----------------
__global__ __launch_bounds__(256) void k_gather_last(const int* __restrict__ row_start, const int* __restrict__ deg,
                                                     const int* __restrict__ csr_src,
                                                     const unsigned short* __restrict__ hs_in,
                                                     const float* __restrict__ nrm,
                                                     const float* __restrict__ res2,
                                                     float* h0io) {
  int wid = threadIdx.x >> 6, lane = threadIdx.x & 63;
  int n = blockIdx.x * 4 + wid;
  if (n >= NN) return;
  float a0, a1, a2, a3;
  gather_accum(row_start, deg, csr_src, hs_in, n, wid, lane, a0, a1, a2, a3);
  if (lane < 16) {
    size_t o = (size_t)n * 64 + (lane << 2);
    float nn_ = nrm[n];
    float4 h4 = *(const float4*)&h0io[o];
    float4 r4 = *(const float4*)&res2[o];
    float hn = 0.5f * nn_;
    float4 v;
    v.x = fmaf(hn, a0, 0.5f * h4.x) + r4.x;
    v.y = fmaf(hn, a1, 0.5f * h4.y) + r4.y;
    v.z = fmaf(hn, a2, 0.5f * h4.z) + r4.z;
    v.w = fmaf(hn, a3, 0.5f * h4.w) + r4.w;
    *(float4*)&h0io[o] = v;
  }
}

// ---------------- BN partial sums (pure reduction over hfin f32) ----------------
__global__ __launch_bounds__(256) void k_finred(const float* __restrict__ hfin, float* __restrict__ bn) {
  __shared__ float s1[256], s2[256];
  int d = threadIdx.x & 63;
  int rb = blockIdx.x * 64;
  float sum = 0.f, sq = 0.f;
  for (int r = threadIdx.x >> 6; r < 64; r += 4) {
    int n = rb + r;
    if (n < NN) {
      float v = hfin[(size_t)n * 64 + d];
      sum += v; sq += v * v;
    }
  }
  s1[threadIdx.x] = sum; s2[threadIdx.x] = sq;
  __syncthreads();
  if (threadIdx.x < 128) { s1[threadIdx.x] += s1[threadIdx.x + 128]; s2[threadIdx.x] += s2[threadIdx.x + 128]; }
  __syncthreads();
  if (threadIdx.x < 64) {
    atomicAdd(&bn[d], s1[threadIdx.x] + s1[threadIdx.x + 64]);
    atomicAdd(&bn[64 + d], s2[threadIdx.x] + s2[threadIdx.x + 64]);
  }
}

__global__ void k_bnstats(const float* __restrict__ bn, const float* __restrict__ gamma,
                          const float* __restrict__ beta, float* __restrict__ bns) {
  int d = threadIdx.x;
  float mu = bn[d] * (1.0f / NN);
  float var = fmaxf(bn[64 + d] * (1.0f / NN) - mu * mu, 0.f);
  float sc = rsqrtf(var + 1e-5f) * gamma[d];
  bns[d] = sc;
  bns[64 + d] = beta[d] - mu * sc;
}

__global__ __launch_bounds__(256) void k_bnapply(const float* __restrict__ h, const float* __restrict__ bns,
                                                 float* __restrict__ out) {
  int i = blockIdx.x * 256 + threadIdx.x;
  if (i < NN * 64) {
    int d = i & 63;
    out[i] = fmaf(h[i], bns[d], bns[64 + d]);
  }
}

extern "C" void kernel_launch(void* const* d_in, const int* in_sizes, int n_in,
                              void* d_out, int out_size, void* d_ws, size_t ws_size,
                              hipStream_t stream) {
  const float* node_feats = (const float*)d_in[0];
  const int* src = (const int*)d_in[1];
  const int* dst = (const int*)d_in[2];
  const float* W_fc = (const float*)d_in[3];
  const float* attn_l = (const float*)d_in[4];
  const float* attn_r = (const float*)d_in[5];
  const float* W_res_gat = (const float*)d_in[6];
  const float* gat_bias = (const float*)d_in[7];
  const float* conv_w = (const float*)d_in[8];
  const float* conv_b = (const float*)d_in[9];
  const float* W_res = (const float*)d_in[10];
  const float* b_res = (const float*)d_in[11];
  const float* gamma = (const float*)d_in[12];
  const float* beta = (const float*)d_in[13];
  float* out = (float*)d_out;

  char* base = (char*)d_ws;
  size_t off = 0;
  auto alloc = [&](size_t bytes) -> char* {
    char* p = base + off;
    off = (off + bytes + 255) & ~(size_t)255;
    return p;
  };
  unsigned* feat8u        = (unsigned*)alloc((size_t)NN * 256);                  // 25.6 MB fp8 (n,d,h)
  unsigned short* resval2 = (unsigned short*)alloc((size_t)NN * 256 * 2);        // 51.2 MB bf16; res2 f32 aliases after k_gat
  float* res2             = (float*)resval2;
  float* el               = (float*)alloc((size_t)NN * 4 * 4);
  float* er               = (float*)alloc((size_t)NN * 4 * 4);
  float* h0               = (float*)alloc((size_t)NN * 64 * 4);                  // 25.6 MB; Abf aliases BEFORE k_gat; hfin at end
  unsigned short* Abf     = (unsigned short*)h0;
  unsigned short* hsA     = (unsigned short*)alloc((size_t)(NN + 1) * 64 * 2);   // 12.8 MB bf16 + dummy row
  unsigned short* hsB     = (unsigned short*)alloc((size_t)(NN + 1) * 64 * 2);
  int* csr_src            = (int*)alloc((size_t)NE * 4);
  float* nrm              = (float*)alloc((size_t)NN * 4);
  int* row_start          = (int*)alloc((size_t)NN * 4);
  unsigned short* Bpacked = (unsigned short*)alloc((size_t)4 * 16384 * 2);
  float* w_elr            = (float*)alloc((size_t)8 * 128 * 4);
  size_t zoff = off;
  int* deg                = (int*)alloc((size_t)NN * 4);
  int* cursor             = (int*)alloc((size_t)NN * 4);
  int* counter            = (int*)alloc(256);
  float* bn               = (float*)alloc(256 * 4);
  float* hfin             = h0;

  int zwords = (int)((off - zoff) / 4);
  int gE = (NE + 255) / 256;
  int gN = (NN + 255) / 256;
  int gW = (NN + 3) / 4;
  int gM = (NN + 63) / 64;
  int gV = (NN * 64 + 255) / 256;

  k_zero<<<(zwords + 255) / 256, 256, 0, stream>>>((int*)(base + zoff), zwords);
  k_zrow<<<1, 64, 0, stream>>>(hsA, hsB);
  k_deg<<<gE, 256, 0, stream>>>(dst, deg);
  k_alloc<<<gN, 256, 0, stream>>>(deg, row_start, counter, nrm);
  k_scatter<<<gE, 256, 0, stream>>>(src, dst, row_start, cursor, csr_src);

  k_cast<<<(NN * 128 / 4 + 255) / 256, 256, 0, stream>>>(node_feats, Abf);
  k_prepB<<<dim3(8, 4), 256, 0, stream>>>(W_fc, W_res_gat, Bpacked);
  k_prepw<<<4, 256, 0, stream>>>(W_fc, attn_l, attn_r, w_elr);
  k_gemm_mfma<<<dim3((NN + 127) / 128, 4), 256, 0, stream>>>(Abf, Bpacked, feat8u, resval2);

  k_elr2<<<(NN + 31) / 32, 256, 0, stream>>>(node_feats, w_elr, el, er);
  k_gat<<<gW, 256, 0, stream>>>(row_start, deg, csr_src, el, er, feat8u, resval2,
                                gat_bias, conv_w, conv_b, nrm, h0, hsA);

  // resval2 dead now; res2 (f32) reuses its space
  k_gemm_nt_bias_relu<<<gM, 256, 0, stream>>>(node_feats, W_res, b_res, res2);

  k_gather_mid<<<gW, 256, 0, stream>>>(row_start, deg, csr_src, hsA, nrm, h0, hsB);
  k_gather_mid<<<gW, 256, 0, stream>>>(row_start, deg, csr_src, hsB, nrm, h0, hsA);
  k_gather_mid<<<gW, 256, 0, stream>>>(row_start, deg, csr_src, hsA, nrm, h0, hsB);
  k_gather_mid<<<gW, 256, 0, stream>>>(row_start, deg, csr_src, hsB, nrm, h0, hsA);
  // last step fused with residual add: writes hfin (= h0) in f32
  k_gather_last<<<gW, 256, 0, stream>>>(row_start, deg, csr_src, hsA, nrm, res2, hfin);

  k_finred<<<gM, 256, 0, stream>>>(hfin, bn);
  k_bnstats<<<1, 64, 0, stream>>>(bn, gamma, beta, bn + 128);
  k_bnapply<<<gV, 256, 0, stream>>>(hfin, bn + 128, out);
}